// Round 2
// baseline (317.003 us; speedup 1.0000x reference)
//
#include <hip/hip_runtime.h>

// MovingAverageLayer: x (T=262144, F=64) fp32 -> out (T, 4F) fp32
// out[:, 0:64]=x, out[:,64:128]=ma7, out[:,128:192]=ma30, out[:,192:256]=ma90
// (windowed mean for i>=p-1, expanding mean cumsum[i]/(i+1) for i<p-1)
//
// Persistent ring-buffer version:
//  - 512 blocks x 512 threads; each block owns 512 consecutive rows
//    (4 tiles of 128). LDS is a 256-row ring (64 KB, slot = gi & 255).
//  - The 90-row halo is staged ONCE per block; each subsequent tile reuses
//    the previous tile's tail already in the ring. Read traffic:
//    67 MB input + 512 blocks * 90 rows * 256 B = 79 MB (1.18x) vs 114 MB
//    for per-tile halos.
//  - Per tile: 8 strips x 64 cols; each thread re-seeds its three window
//    sums from 90 LDS rows, then runs a 16-row sliding scan. Column reads
//    are 2-way bank aliasing only (free). Writes are 4 x 256 B coalesced
//    wave segments per row (full cache lines).
//  - 64 KB LDS -> exactly 2 blocks/CU (16 waves/CU); grid 512 = 2/CU
//    resident, so stage(t+1) of one block overlaps compute(t) of the other.

#define T_ROWS 262144
#define F_COLS 64
#define OUT_COLS 256
#define TILE 128
#define HALO 90
#define NT 4                        // tiles per block
#define BLOCK_ROWS (TILE * NT)      // 512
#define RING 256                    // ring rows (power of 2, >= TILE+TILE)
#define RMASK (RING - 1)
#define THREADS 512
#define STRIPS 8
#define STRIP_ROWS (TILE / STRIPS)  // 16

__global__ __launch_bounds__(THREADS) void ma_kernel(const float* __restrict__ x,
                                                     float* __restrict__ out) {
    __shared__ float lds[RING * F_COLS];        // 65536 B

    const int tid  = threadIdx.x;
    const int base = blockIdx.x * BLOCK_ROWS;   // first output row of block

    float4* lds4 = (float4*)lds;
    const float4* __restrict__ x4 = (const float4*)x;

    // ---- prologue: stage rows [base-90, base+128) into ring slots ----
    if (base >= HALO) {
        for (int idx = tid; idx < (HALO + TILE) * (F_COLS / 4); idx += THREADS) {
            int r  = idx >> 4;                  // staged row 0..217
            int c4 = idx & 15;
            int gi = base - HALO + r;
            lds4[(gi & RMASK) * 16 + c4] = x4[gi * 16 + c4];
        }
    } else {
        // block 0: rows < 0 are zero (makes windowed sum == cumsum diff)
        for (int idx = tid; idx < (HALO + TILE) * (F_COLS / 4); idx += THREADS) {
            int r  = idx >> 4;
            int c4 = idx & 15;
            int gi = base - HALO + r;
            float4 v = make_float4(0.f, 0.f, 0.f, 0.f);
            if (gi >= 0) v = x4[gi * 16 + c4];
            lds4[(gi & RMASK) * 16 + c4] = v;
        }
    }
    __syncthreads();

    const int col   = tid & 63;
    const int strip = tid >> 6;                 // wave-uniform
    const float* lc = lds + col;                // column ptr, stride 64
    float* oc = out + col;
    const float r7 = 1.f / 7.f, r30 = 1.f / 30.f, r90 = 1.f / 90.f;

    for (int t = 0; t < NT; ++t) {
        const int g0  = base + t * TILE + strip * STRIP_ROWS; // first row of strip
        const int lr0 = g0 & RMASK;

        // warm-up: seed window sums from the 90 preceding ring rows
        float s7 = 0.f, s30 = 0.f, s90 = 0.f;
        #pragma unroll
        for (int k = 1; k <= 7; ++k)  s7  += lc[((lr0 - k) & RMASK) * F_COLS];
        s30 = s7;
        #pragma unroll
        for (int k = 8; k <= 30; ++k) s30 += lc[((lr0 - k) & RMASK) * F_COLS];
        s90 = s30;
        #pragma unroll
        for (int k = 31; k <= 90; ++k) s90 += lc[((lr0 - k) & RMASK) * F_COLS];

        if (g0 < 89) {
            // block 0, tile 0 only: expanding denominators min(gi+1, p)
            for (int j = 0; j < STRIP_ROWS; ++j) {
                int gi = g0 + j;
                int lr = gi & RMASK;
                float v   = lc[lr * F_COLS];
                float o7  = lc[((lr - 7)  & RMASK) * F_COLS];
                float o30 = lc[((lr - 30) & RMASK) * F_COLS];
                float o90 = lc[((lr - 90) & RMASK) * F_COLS];
                s7 += v - o7; s30 += v - o30; s90 += v - o90;
                float fi  = (float)(gi + 1);
                float d7  = (gi < 6)  ? fi : 7.f;
                float d30 = (gi < 29) ? fi : 30.f;
                float d90 = (gi < 89) ? fi : 90.f;
                float* o = oc + gi * OUT_COLS;
                o[0]   = v;
                o[64]  = s7  / d7;
                o[128] = s30 / d30;
                o[192] = s90 / d90;
            }
        } else {
            #pragma unroll
            for (int j = 0; j < STRIP_ROWS; ++j) {
                int gi = g0 + j;
                int lr = gi & RMASK;
                float v   = lc[lr * F_COLS];
                float o7  = lc[((lr - 7)  & RMASK) * F_COLS];
                float o30 = lc[((lr - 30) & RMASK) * F_COLS];
                float o90 = lc[((lr - 90) & RMASK) * F_COLS];
                s7 += v - o7; s30 += v - o30; s90 += v - o90;
                float* o = oc + gi * OUT_COLS;
                o[0]   = v;
                o[64]  = s7  * r7;
                o[128] = s30 * r30;
                o[192] = s90 * r90;
            }
        }

        __syncthreads();            // all ring reads for tile t complete
        if (t + 1 < NT) {
            // stage tile t+1 (overwrites slots of tile t-1, now dead)
            const int nbase = base + (t + 1) * TILE;
            for (int idx = tid; idx < TILE * (F_COLS / 4); idx += THREADS) {
                int r  = idx >> 4;
                int c4 = idx & 15;
                int gi = nbase + r;
                lds4[(gi & RMASK) * 16 + c4] = x4[gi * 16 + c4];
            }
            __syncthreads();        // tile t+1 visible before its compute
        }
    }
}

extern "C" void kernel_launch(void* const* d_in, const int* in_sizes, int n_in,
                              void* d_out, int out_size, void* d_ws, size_t ws_size,
                              hipStream_t stream) {
    const float* x = (const float*)d_in[0];
    float* out = (float*)d_out;
    const int n_blocks = T_ROWS / BLOCK_ROWS;   // 512
    ma_kernel<<<n_blocks, THREADS, 0, stream>>>(x, out);
}

// Round 3
// 305.261 us; speedup vs baseline: 1.0385x; 1.0385x over previous
//
#include <hip/hip_runtime.h>

// MovingAverageLayer: x (T=262144, F=64) fp32 -> out (T, 4F) fp32
// out[:, 0:64]=x, out[:,64:128]=ma7, out[:,128:192]=ma30, out[:,192:256]=ma90
// (windowed mean for i>=p-1, expanding mean cumsum[i]/(i+1) for i<p-1)
//
// Round-1 block-cooperative LDS structure (measured best: 312.7 us) plus
// non-temporal output stores:
//  - Each block stages rows [base-90, base+128) (218 rows x 256B = 55.8 KB)
//    into LDS once, zero-filling the halo for block 0 (makes windowed sum
//    == cumsum diff for all rows; only denominators differ in the
//    expanding region).
//  - 512 threads = 8 strips x 64 cols, 16-row sliding scan per thread,
//    all window reads from LDS (2-way bank aliasing only = free).
//  - NEW: output is write-once / never re-read -> nontemporal stores keep
//    the 268 MB write stream from evicting the input tail out of L2, so
//    the 90-row halo (= block b-1's freshly-fetched main tile) becomes an
//    L2 hit instead of an HBM re-fetch.
//  - 55.8 KB LDS -> 2 blocks/CU -> 16 waves/CU (4/SIMD); 2048 blocks.

#define T_ROWS 262144
#define F_COLS 64
#define OUT_COLS 256
#define TILE 128                    // output rows per block
#define HALO 90
#define STAGE_ROWS (TILE + HALO)    // 218
#define THREADS 512
#define STRIPS 8                    // THREADS / 64
#define STRIP_ROWS (TILE / STRIPS)  // 16

__global__ __launch_bounds__(THREADS) void ma_kernel(const float* __restrict__ x,
                                                     float* __restrict__ out) {
    __shared__ float lds[STAGE_ROWS * F_COLS];   // 55808 B

    const int tid = threadIdx.x;
    const long base = (long)blockIdx.x * TILE;

    // ---- stage rows [base-HALO, base+TILE) into LDS (zero-fill row < 0) ----
    {
        const long g0f = (base - HALO) * F_COLS;     // global float idx of lds[0]
        float4* lds4 = (float4*)lds;
        const int n4 = STAGE_ROWS * F_COLS / 4;      // 3488 float4s
        if (base >= HALO) {
            // fully in-range: contiguous 55.8 KB copy, coalesced float4
            const float4* __restrict__ src = (const float4*)(x + g0f);
            for (int idx = tid; idx < n4; idx += THREADS)
                lds4[idx] = src[idx];
        } else {
            // block 0: rows below 0 -> zeros (boundary is float4-aligned:
            // g0f = -5760, so gf crosses 0 exactly at idx = 1440)
            for (int idx = tid; idx < n4; idx += THREADS) {
                long gf = g0f + (long)idx * 4;
                float4 v = make_float4(0.f, 0.f, 0.f, 0.f);
                if (gf >= 0) v = *(const float4*)(x + gf);
                lds4[idx] = v;
            }
        }
    }
    __syncthreads();

    // ---- sliding scan: strip = tid>>6 (wave-uniform), col = tid&63 ----
    const int col   = tid & 63;
    const int strip = tid >> 6;
    const int lr0   = HALO + strip * STRIP_ROWS;     // first local row of strip
    const long g0   = base + strip * STRIP_ROWS;     // first global row

    const float* __restrict__ lc = lds + col;        // column ptr, stride 64

    // warm-up: seed window sums from the 90 preceding (LDS) rows
    float s7 = 0.f, s30 = 0.f, s90 = 0.f;
    #pragma unroll
    for (int k = 1; k <= 7; ++k)  s7  += lc[(lr0 - k) * F_COLS];
    s30 = s7;
    #pragma unroll
    for (int k = 8; k <= 30; ++k) s30 += lc[(lr0 - k) * F_COLS];
    s90 = s30;
    #pragma unroll
    for (int k = 31; k <= 90; ++k) s90 += lc[(lr0 - k) * F_COLS];

    float* __restrict__ oc = out + col;

    if (g0 < 89) {
        // block 0 only: rows gi <= 88 use expanding denominators min(gi+1, p)
        for (int j = 0; j < STRIP_ROWS; ++j) {
            const int lr = lr0 + j;
            const long gi = g0 + j;
            float v   = lc[lr * F_COLS];
            float o7  = lc[(lr - 7)  * F_COLS];
            float o30 = lc[(lr - 30) * F_COLS];
            float o90 = lc[(lr - 90) * F_COLS];
            s7 += v - o7; s30 += v - o30; s90 += v - o90;
            float fi  = (float)(gi + 1);
            float d7  = (gi < 6)  ? fi : 7.f;
            float d30 = (gi < 29) ? fi : 30.f;
            float d90 = (gi < 89) ? fi : 90.f;
            float* o = oc + gi * OUT_COLS;
            __builtin_nontemporal_store(v,         o);
            __builtin_nontemporal_store(s7  / d7,  o + 64);
            __builtin_nontemporal_store(s30 / d30, o + 128);
            __builtin_nontemporal_store(s90 / d90, o + 192);
        }
    } else {
        const float r7 = 1.f / 7.f, r30 = 1.f / 30.f, r90 = 1.f / 90.f;
        #pragma unroll
        for (int j = 0; j < STRIP_ROWS; ++j) {
            const int lr = lr0 + j;
            float v   = lc[lr * F_COLS];
            float o7  = lc[(lr - 7)  * F_COLS];
            float o30 = lc[(lr - 30) * F_COLS];
            float o90 = lc[(lr - 90) * F_COLS];
            s7 += v - o7; s30 += v - o30; s90 += v - o90;
            float* o = oc + (g0 + j) * OUT_COLS;
            __builtin_nontemporal_store(v,         o);
            __builtin_nontemporal_store(s7  * r7,  o + 64);
            __builtin_nontemporal_store(s30 * r30, o + 128);
            __builtin_nontemporal_store(s90 * r90, o + 192);
        }
    }
}

extern "C" void kernel_launch(void* const* d_in, const int* in_sizes, int n_in,
                              void* d_out, int out_size, void* d_ws, size_t ws_size,
                              hipStream_t stream) {
    const float* x = (const float*)d_in[0];
    float* out = (float*)d_out;
    const int n_blocks = T_ROWS / TILE;   // 2048
    ma_kernel<<<n_blocks, THREADS, 0, stream>>>(x, out);
}